// Round 12
// baseline (7350.539 us; speedup 1.0000x reference)
//
#include <hip/hip_runtime.h>
#include <cfloat>
#include <math.h>

#define B_ 64
#define P_ 196
#define ENC_ 2048
#define D_ 512
#define V_ 32000
#define L_ 32
#define T_ 31

// flat f32 output layout (reference return order)
#define OUT_PREDS 0L
#define OUT_CAPS  63488000L              // 64*31*32000
#define OUT_DECL  63490048L              // +64*32
#define OUT_ALPH  63490112L              // +64
#define OUT_ORDER 63878976L              // +64*31*196

typedef __bf16 bf16;
typedef __bf16 bf16x8 __attribute__((ext_vector_type(8)));
typedef __bf16 bf16x4 __attribute__((ext_vector_type(4)));
typedef __bf16 bf16x2 __attribute__((ext_vector_type(2)));
typedef float  f32x4  __attribute__((ext_vector_type(4)));

static __device__ __forceinline__ float sigmoidf_(float x) { return 1.f / (1.f + __expf(-x)); }

// ------- sort, caps gather, scalar outputs, full-row map (active + inactive) -------
__global__ void k_order(const int* __restrict__ cap_len, const int* __restrict__ caps,
                        int* __restrict__ order_i, int* __restrict__ declen_i,
                        int* __restrict__ caps_i, float* __restrict__ out,
                        int* __restrict__ rmap, int* __restrict__ orow, int* __restrict__ mact)
{
    __shared__ int len_s[B_], dl_s[B_];
    __shared__ int Msh;
    int tid = threadIdx.x;
    len_s[tid] = cap_len[tid];
    __syncthreads();
    int li = len_s[tid];
    int pos = 0;
    for (int j = 0; j < B_; ++j) {
        int lj = len_s[j];
        pos += (lj > li) || (lj == li && j < tid);   // stable descending rank
    }
    order_i[pos]  = tid;
    declen_i[pos] = li - 1;
    dl_s[pos]     = li - 1;
    out[OUT_ORDER + pos] = (float)tid;
    out[OUT_DECL  + pos] = (float)(li - 1);
    for (int l = 0; l < L_; ++l) {
        int tok = caps[tid * L_ + l];
        caps_i[pos * L_ + l] = tok;
        out[OUT_CAPS + pos * L_ + l] = (float)tok;
    }
    __syncthreads();
    int p = tid;
    int off = 0;
    for (int j = 0; j < p; ++j) off += dl_s[j];
    int dl = dl_s[p];
    if (p == B_ - 1) { Msh = off + dl; mact[0] = off + dl; }
    __syncthreads();
    // active slots [off, off+dl): GEMM rows; inactive slots: zero rows (sign-encoded)
    for (int tt = 0; tt < dl; ++tt) {
        rmap[off + tt] = tt * B_ + p;
        orow[off + tt] = p * T_ + tt;
    }
    int ibase = Msh + p * T_ - off;
    for (int tt = dl; tt < T_; ++tt) {
        rmap[ibase + (tt - dl)] = 0;
        orow[ibase + (tt - dl)] = -(p * T_ + tt) - 1;
    }
}

// ---------------- merged f32 -> bf16 convert (plain row-major mats) ----------------
struct CvtSegs { const float* s[4]; bf16* d[4]; long cum[5]; };
__global__ __launch_bounds__(256) void k_cvt_all(CvtSegs cs)
{
    long i8 = ((long)blockIdx.x * 256 + threadIdx.x) * 8;
    if (i8 >= cs.cum[4]) return;
    int k = 0;
    while (i8 >= cs.cum[k + 1]) ++k;
    long loc = i8 - cs.cum[k];
    const float* src = cs.s[k] + loc;
    float4 a = *(const float4*)(src);
    float4 b = *(const float4*)(src + 4);
    bf16x8 v;
    v[0]=(bf16)a.x; v[1]=(bf16)a.y; v[2]=(bf16)a.z; v[3]=(bf16)a.w;
    v[4]=(bf16)b.x; v[5]=(bf16)b.y; v[6]=(bf16)b.z; v[7]=(bf16)b.w;
    *(bf16x8*)(cs.d[k] + loc) = v;
}

// ------- pack f32 weights -> MFMA-fragment-ordered bf16 -------
// layout: dst[(n>>4)*Kv*16 + (k>>3)*128 + (n&15)*8 + (k&7)]
// MODE 0: plain s1[N][Kv]; 2: K-split at Ksp
template<int MODE>
__global__ __launch_bounds__(256)
void k_packB(const float* __restrict__ s1, const float* __restrict__ s2,
             bf16* __restrict__ dst, int Kv, int Ksp)
{
    const int ntile = blockIdx.x, tid = threadIdx.x;
    long tbase = (long)ntile * Kv * 16;
    const int groups = Kv * 2;                    // (Kv/8) * 16
    for (int g = tid; g < groups; g += 256) {
        int kkq = g >> 4, r16 = g & 15;
        int n = ntile * 16 + r16, k0 = kkq * 8;
        const float* src;
        if (MODE == 0) src = s1 + (long)n * Kv + k0;
        else           src = (k0 < Ksp) ? s1 + (long)n * Ksp + k0
                                        : s2 + (long)n * (Kv - Ksp) + (k0 - Ksp);
        float4 a = *(const float4*)src;
        float4 b = *(const float4*)(src + 4);
        bf16x8 v;
        v[0]=(bf16)a.x; v[1]=(bf16)a.y; v[2]=(bf16)a.z; v[3]=(bf16)a.w;
        v[4]=(bf16)b.x; v[5]=(bf16)b.y; v[6]=(bf16)b.z; v[7]=(bf16)b.w;
        *(bf16x8*)(dst + tbase + (long)kkq * 128 + r16 * 8) = v;
    }
}

// ------- pack hseq (gathered by rmap) -> fragment order for preds A -------
__global__ __launch_bounds__(256)
void k_packA(const bf16* __restrict__ hseq, const int* __restrict__ rmap, bf16* __restrict__ dst)
{
    const int mt = blockIdx.x, tid = threadIdx.x;
    long tbase = (long)mt * 32768;
    for (int g = tid; g < 4096; g += 256) {       // mi(4) x kkq(64) x r16(16)
        int mi = g >> 10, rem = g & 1023, kkq = rem >> 4, r16 = rem & 15;
        int row = rmap[mt * 64 + mi * 16 + r16];
        bf16x8 v = *(const bf16x8*)(hseq + (long)row * 512 + kkq * 8);
        *(bf16x8*)(dst + tbase + mi * 8192 + (long)kkq * 128 + r16 * 8) = v;
    }
}

// --- enc gather-by-order -> bf16, DUAL write: row-major enc_s + fragment enc_pk ---
__global__ __launch_bounds__(256) void k_cvt_enc(const float* __restrict__ enc,
                                                 const int* __restrict__ order_i,
                                                 bf16* __restrict__ enc_s,
                                                 bf16* __restrict__ enc_pk)
{
    long i = ((long)blockIdx.x * 256 + threadIdx.x) * 8;
    int r = (int)(i >> 11);                 // global sorted row (b*196+p)
    int k0 = (int)(i & 2047);
    int b = (int)(i / ((long)P_ * ENC_));
    long rem = i - (long)b * P_ * ENC_;
    const float* src = enc + (long)order_i[b] * P_ * ENC_ + rem;
    float4 a = *(const float4*)(src);
    float4 c = *(const float4*)(src + 4);
    bf16x8 v;
    v[0]=(bf16)a.x; v[1]=(bf16)a.y; v[2]=(bf16)a.z; v[3]=(bf16)a.w;
    v[4]=(bf16)c.x; v[5]=(bf16)c.y; v[6]=(bf16)c.z; v[7]=(bf16)c.w;
    *(bf16x8*)(enc_s + i) = v;
    *(bf16x8*)(enc_pk + (long)(r >> 4) * 32768 + (long)(k0 >> 3) * 128 + (r & 15) * 8) = v;
}

// ---------------- mean over pixels ----------------
__global__ __launch_bounds__(256) void k_meanb(const bf16* __restrict__ enc_s, bf16* __restrict__ mean_b)
{
    int b = blockIdx.x, col = blockIdx.y * 256 + threadIdx.x;
    float s = 0.f;
    const bf16* eb = enc_s + (long)b * P_ * ENC_ + col;
    for (int p = 0; p < P_; ++p) s += (float)eb[(long)p * ENC_];
    mean_b[(long)b * ENC_ + col] = (bf16)(s * (1.f / (float)P_));
}

// ---------------- MFMA GEMM: C[M][N] = A[M][K](bf16) * B[N][K]^T(bf16) ------
// 256 thr = 4 waves; tile (MI*16) x 128; swapped-operand mfma -> dwordx4 stores.
// PK=1: B fragment-packed. PA=1: A fragment-packed.
// FUSE: 0=single B, 1=N-split at Nsp. EPI: 0=RAW f32 slot z, 1=bf16 +bias.
// SWZ:  0=3D grid; 1=att1 784 blocks XCD-chunked mt-major
template<int MI, int FUSE, int EPI, int SWZ, int PK, int PA>
__global__ void __launch_bounds__(256)
k_mgemm(const bf16* __restrict__ A, long lda,
        const bf16* __restrict__ B1, const bf16* __restrict__ B2,
        const float* __restrict__ bias,
        float* __restrict__ Cf, bf16* __restrict__ Cb,
        int N, int K, int kspl, int Nsp, int Mtot)
{
    const int tid = threadIdx.x;
    const int lane = tid & 63, w = tid >> 6;
    int mt, nt, z;
    if (SWZ == 0) { mt = blockIdx.x; nt = blockIdx.y; z = blockIdx.z; }
    else          { int o = blockIdx.x; int wg = (o & 7) * 98 + (o >> 3);
                    mt = wg >> 2; nt = wg & 3; z = 0; }
    const int krange = K / kspl;
    const int k0 = z * krange, k1 = k0 + krange;
    const int r16 = lane & 15, kq = lane >> 4;
    const int koff = kq * 8;

    const bf16* Ap[MI];
#pragma unroll
    for (int mi = 0; mi < MI; ++mi) {
        if (PA) Ap[mi] = A + (long)(mt * MI + mi) * ((long)K * 16) + kq * 128 + r16 * 8;
        else    Ap[mi] = A + (long)(mt * (MI * 16) + mi * 16 + r16) * lda + koff;
    }
    const int ncol0 = nt * 128 + w * 32;

    const bf16* Bp[2];
#pragma unroll
    for (int ni = 0; ni < 2; ++ni) {
        if (PK) {
            Bp[ni] = B1 + (long)((ncol0 + ni * 16) >> 4) * ((long)K * 16) + kq * 128 + r16 * 8;
        } else {
            int n = ncol0 + ni * 16 + r16;
            if (FUSE == 1)
                Bp[ni] = (n < Nsp) ? B1 + (long)n * K + koff
                                   : B2 + (long)(n - Nsp) * K + koff;
            else
                Bp[ni] = B1 + (long)n * K + koff;
        }
    }

    auto loadA = [&](int kk, bf16x8* dst) {
#pragma unroll
        for (int mi = 0; mi < MI; ++mi)
            dst[mi] = PA ? *(const bf16x8*)(Ap[mi] + (long)kk * 16)
                         : *(const bf16x8*)(Ap[mi] + kk);
    };
    auto loadB = [&](int kk, bf16x8* dst) {
#pragma unroll
        for (int ni = 0; ni < 2; ++ni)
            dst[ni] = PK ? *(const bf16x8*)(Bp[ni] + (long)kk * 16)
                         : *(const bf16x8*)(Bp[ni] + kk);
    };

    f32x4 acc[MI][2] = {};
    bf16x8 af[MI], bfr[2];
    loadA(k0, af); loadB(k0, bfr);
    for (int kk = k0 + 32; kk < k1; kk += 32) {
        bf16x8 af2[MI], bf2[2];
        loadA(kk, af2); loadB(kk, bf2);
#pragma unroll
        for (int mi = 0; mi < MI; ++mi)
#pragma unroll
            for (int ni = 0; ni < 2; ++ni)
                acc[mi][ni] = __builtin_amdgcn_mfma_f32_16x16x32_bf16(bfr[ni], af[mi], acc[mi][ni], 0, 0, 0);
#pragma unroll
        for (int mi = 0; mi < MI; ++mi) af[mi] = af2[mi];
#pragma unroll
        for (int ni = 0; ni < 2; ++ni) bfr[ni] = bf2[ni];
    }
#pragma unroll
    for (int mi = 0; mi < MI; ++mi)
#pragma unroll
        for (int ni = 0; ni < 2; ++ni)
            acc[mi][ni] = __builtin_amdgcn_mfma_f32_16x16x32_bf16(bfr[ni], af[mi], acc[mi][ni], 0, 0, 0);

#pragma unroll
    for (int mi = 0; mi < MI; ++mi) {
        const int row = mt * (MI * 16) + mi * 16 + r16;
#pragma unroll
        for (int ni = 0; ni < 2; ++ni) {
            const int col = ncol0 + ni * 16 + kq * 4;
            f32x4 v = acc[mi][ni];
            if (EPI == 0) {
                *(f32x4*)(Cf + (long)z * Mtot * N + (long)row * N + col) = v;
            } else {
                f32x4 bv = *(const f32x4*)(bias + col);
                bf16x4 o;
                o[0]=(bf16)(v[0]+bv[0]); o[1]=(bf16)(v[1]+bv[1]);
                o[2]=(bf16)(v[2]+bv[2]); o[3]=(bf16)(v[3]+bv[3]);
                *(bf16x4*)(Cb + (long)row * N + col) = o;
            }
        }
    }
}

// ------- att2|gate matvec from h in LDS: wave-per-row, coalesced 1KB row reads -------
static __device__ __forceinline__ void att2_mv(const float* h_s, const bf16* Wab_rm,
                                               float* att2g, int b)
{
    const int tid = threadIdx.x;
    const int lane = tid & 63, wv = tid >> 6;
    float h8[8];
#pragma unroll
    for (int q = 0; q < 8; ++q) h8[q] = h_s[lane * 8 + q];
    for (int r = wv; r < 2560; r += 8) {
        bf16x8 w8 = *(const bf16x8*)(Wab_rm + (long)r * 512 + lane * 8);
        float p = 0.f;
#pragma unroll
        for (int q = 0; q < 8; ++q) p += h8[q] * (float)w8[q];
#pragma unroll
        for (int off = 32; off > 0; off >>= 1) p += __shfl_xor(p, off);
        if (lane == 0) att2g[(long)b * 2560 + r] = p;
    }
}

// ---------------- init h,c = LN(mean_enc @ W^T + b) + att2g(t=0) ----------------
__global__ __launch_bounds__(512)
void k_initln(const float* __restrict__ pi,
              const float* __restrict__ b_h, const float* __restrict__ b_c,
              const float* __restrict__ g_h, const float* __restrict__ be_h,
              const float* __restrict__ g_c, const float* __restrict__ be_c,
              const bf16* __restrict__ Wab_rm,
              bf16* __restrict__ xh, float* __restrict__ cbuf, float* __restrict__ att2g)
{
    int b = blockIdx.x, d = threadIdx.x;
    float yh = pi[(long)b * 1024 + d]       + b_h[d];
    float yc = pi[(long)b * 1024 + 512 + d] + b_c[d];
    __shared__ float r1[512], r2[512], r3[512], r4[512], h_s[512];
    r1[d] = yh; r2[d] = yh * yh; r3[d] = yc; r4[d] = yc * yc;
    __syncthreads();
    for (int s = 256; s > 0; s >>= 1) {
        if (d < s) { r1[d]+=r1[d+s]; r2[d]+=r2[d+s]; r3[d]+=r3[d+s]; r4[d]+=r4[d+s]; }
        __syncthreads();
    }
    float mh = r1[0] * (1.f/512.f), vh = r2[0] * (1.f/512.f) - mh*mh;
    float mc = r3[0] * (1.f/512.f), vc = r4[0] * (1.f/512.f) - mc*mc;
    float hln = (yh - mh) * rsqrtf(vh + 1e-5f) * g_h[d] + be_h[d];
    float cln = (yc - mc) * rsqrtf(vc + 1e-5f) * g_c[d] + be_c[d];
    xh[(long)b * 3072 + 2560 + d] = (bf16)hln;
    cbuf[(long)b * 512 + d] = cln;
    h_s[d] = hln;
    __syncthreads();
    att2_mv(h_s, Wab_rm, att2g, b);
}

// ------- fused attention: alpha + awe*gate + emb; 128 blocks = (b, seg of 1024 cols) -------
// att2g: single slot [64][2560] f32 ([0:512]=att2 raw, [512:2560]=gate raw)
__global__ __launch_bounds__(512)
void k_attn(const float* __restrict__ att2g, const float* __restrict__ b_dec,
            const float* __restrict__ b_beta, const float* __restrict__ Wfull,
            const bf16* __restrict__ att1_b, const bf16* __restrict__ enc_s,
            const int* __restrict__ caps_i, const int* __restrict__ declen_i,
            const float* __restrict__ emb,
            bf16* __restrict__ xh, float* __restrict__ out, int t)
{
    const int b = blockIdx.x >> 1, seg = blockIdx.x & 1, tid = threadIdx.x;
    if (t >= declen_i[b]) {
        if (seg == 1 && tid < P_) out[OUT_ALPH + ((long)b * T_ + t) * P_ + tid] = 0.f;
        return;
    }
    __shared__ float att2s[512], wf[512], red[512], alp[P_];
    att2s[tid] = att2g[(long)b * 2560 + tid] + b_dec[tid];
    wf[tid] = Wfull[tid];
    __syncthreads();
    float ev = -FLT_MAX;
    if (tid < P_) {
        const bf16* ar = att1_b + ((long)b * P_ + tid) * 512;
        float acc = 0.f;
        for (int a0 = 0; a0 < 512; a0 += 8) {
            bf16x8 v = *(const bf16x8*)(ar + a0);
#pragma unroll
            for (int j = 0; j < 8; ++j)
                acc += fmaxf((float)v[j] + att2s[a0 + j], 0.f) * wf[a0 + j];
        }
        ev = acc;   // + b_full: softmax-invariant
    }
    red[tid] = ev;
    __syncthreads();
    for (int s = 256; s > 0; s >>= 1) { if (tid < s) red[tid] = fmaxf(red[tid], red[tid + s]); __syncthreads(); }
    float mx = red[0];
    __syncthreads();
    float ex = (tid < P_) ? __expf(ev - mx) : 0.f;
    red[tid] = ex;
    __syncthreads();
    for (int s = 256; s > 0; s >>= 1) { if (tid < s) red[tid] += red[tid + s]; __syncthreads(); }
    float inv = 1.f / red[0];
    if (tid < P_) alp[tid] = ex * inv;
    __syncthreads();
    if (seg == 1 && tid < P_)
        out[OUT_ALPH + ((long)b * T_ + t) * P_ + tid] = alp[tid];
    // awe for this 1024-col segment (bf16x2 per thread)
    const int c0 = seg * 1024 + tid * 2;
    const bf16* eb = enc_s + (long)b * P_ * ENC_ + c0;
    float a0 = 0.f, a1 = 0.f;
#pragma unroll 4
    for (int p = 0; p < P_; ++p) {
        bf16x2 v = *(const bf16x2*)(eb + (long)p * ENC_);
        float al = alp[p];
        a0 += al * (float)v[0]; a1 += al * (float)v[1];
    }
    float g0 = b_beta[c0]     + att2g[(long)b * 2560 + 512 + c0];
    float g1 = b_beta[c0 + 1] + att2g[(long)b * 2560 + 512 + c0 + 1];
    bf16x2 o;
    o[0] = (bf16)(a0 * sigmoidf_(g0));
    o[1] = (bf16)(a1 * sigmoidf_(g1));
    *(bf16x2*)(xh + (long)b * 3072 + 512 + c0) = o;
    if (seg == 0) {
        int tok = caps_i[b * L_ + t];
        xh[(long)b * 3072 + tid] = (bf16)emb[(long)tok * 512 + tid];
    }
}

// ---- LSTM + 2x LN + state update + hseq + NEXT-step att2|gate matvec (fused) ----
__global__ __launch_bounds__(512)
void k_lstm(const float* __restrict__ gp, const float* __restrict__ b_ih, const float* __restrict__ b_hh,
            const float* __restrict__ g_h, const float* __restrict__ be_h,
            const float* __restrict__ g_c, const float* __restrict__ be_c,
            const bf16* __restrict__ Wab_rm,
            bf16* __restrict__ xh, float* __restrict__ cbuf, bf16* __restrict__ hseq,
            float* __restrict__ att2g, const int* __restrict__ declen_i, int t)
{
    int b = blockIdx.x, d = threadIdx.x;
    if (t >= declen_i[b]) return;
    float iv = b_ih[d]        + b_hh[d];
    float fv = b_ih[512 + d]  + b_hh[512 + d];
    float gv = b_ih[1024 + d] + b_hh[1024 + d];
    float ov = b_ih[1536 + d] + b_hh[1536 + d];
#pragma unroll
    for (int s = 0; s < 8; ++s) {
        const float* gs = gp + ((long)s * B_ + b) * 2048;
        iv += gs[d]; fv += gs[512 + d]; gv += gs[1024 + d]; ov += gs[1536 + d];
    }
    float cn = sigmoidf_(fv) * cbuf[(long)b * 512 + d] + sigmoidf_(iv) * tanhf(gv);
    float hn = sigmoidf_(ov) * tanhf(cn);
    __shared__ float r1[512], r2[512], r3[512], r4[512], h_s[512];
    r1[d] = hn; r2[d] = hn * hn; r3[d] = cn; r4[d] = cn * cn;
    __syncthreads();
    for (int s = 256; s > 0; s >>= 1) {
        if (d < s) { r1[d]+=r1[d+s]; r2[d]+=r2[d+s]; r3[d]+=r3[d+s]; r4[d]+=r4[d+s]; }
        __syncthreads();
    }
    float mh = r1[0] * (1.f/512.f), vh = r2[0] * (1.f/512.f) - mh*mh;
    float mc = r3[0] * (1.f/512.f), vc = r4[0] * (1.f/512.f) - mc*mc;
    float hln = (hn - mh) * rsqrtf(vh + 1e-5f) * g_h[d] + be_h[d];
    float cln = (cn - mc) * rsqrtf(vc + 1e-5f) * g_c[d] + be_c[d];
    bf16 hv = (bf16)hln;
    xh[(long)b * 3072 + 2560 + d] = hv;
    hseq[((long)t * B_ + b) * 512 + d] = hv;
    cbuf[(long)b * 512 + d] = cln;
    h_s[d] = hln;
    __syncthreads();
    att2_mv(h_s, Wab_rm, att2g, b);    // for step t+1 (skipped reads if b goes inactive)
}

// -------- preds: packed A/B fragment loads; zero-fill merged (sign-encoded orow) --------
__global__ __launch_bounds__(256)
void k_preds(const bf16* __restrict__ Apk, const bf16* __restrict__ Bpk,
             const float* __restrict__ bias, const int* __restrict__ orow,
             const int* __restrict__ mact, float* __restrict__ out)
{
    int o = blockIdx.x; int xcd = o & 7;
    int base = xcd < 6 ? xcd * 969 : 5814 + (xcd - 6) * 968;
    int wg = base + (o >> 3);
    int nt = wg / 31, mt = wg - 31 * nt;
    __shared__ int os[64];
    __shared__ __align__(16) float ct[64][132];
    const int tid = threadIdx.x, lane = tid & 63, w = tid >> 6;
    const int r16 = lane & 15, kq = lane >> 4;
    if (tid < 64) os[tid] = orow[mt * 64 + tid];
    __syncthreads();
    const int r0 = tid >> 5, cc = (tid & 31) * 4;
    const int gcol = nt * 128 + cc;
    if (mt * 64 >= mact[0]) {          // pure-inactive tile: zero-fill only
        f32x4 zz = {0.f, 0.f, 0.f, 0.f};
#pragma unroll
        for (int it = 0; it < 8; ++it) {
            int r = it * 8 + r0;
            int row = -os[r] - 1;
            *(f32x4*)(out + OUT_PREDS + (long)row * V_ + gcol) = zz;
        }
        return;
    }
    const bf16* Ap[4];
#pragma unroll
    for (int mi = 0; mi < 4; ++mi)
        Ap[mi] = Apk + (long)mt * 32768 + mi * 8192 + kq * 128 + r16 * 8;
    const bf16* Bp[2];
#pragma unroll
    for (int ni = 0; ni < 2; ++ni)
        Bp[ni] = Bpk + (long)((nt * 128 + w * 32 + ni * 16) >> 4) * 8192 + kq * 128 + r16 * 8;

    f32x4 acc[4][2] = {};
    bf16x8 af[4], bfr[2];
#pragma unroll
    for (int mi = 0; mi < 4; ++mi) af[mi] = *(const bf16x8*)(Ap[mi]);
#pragma unroll
    for (int ni = 0; ni < 2; ++ni) bfr[ni] = *(const bf16x8*)(Bp[ni]);
    for (int kk = 32; kk < 512; kk += 32) {
        bf16x8 af2[4], bf2[2];
#pragma unroll
        for (int mi = 0; mi < 4; ++mi) af2[mi] = *(const bf16x8*)(Ap[mi] + kk * 16);
#pragma unroll
        for (int ni = 0; ni < 2; ++ni) bf2[ni] = *(const bf16x8*)(Bp[ni] + kk * 16);
#pragma unroll
        for (int mi = 0; mi < 4; ++mi)
#pragma unroll
            for (int ni = 0; ni < 2; ++ni)
                acc[mi][ni] = __builtin_amdgcn_mfma_f32_16x16x32_bf16(bfr[ni], af[mi], acc[mi][ni], 0, 0, 0);
#pragma unroll
        for (int mi = 0; mi < 4; ++mi) af[mi] = af2[mi];
#pragma unroll
        for (int ni = 0; ni < 2; ++ni) bfr[ni] = bf2[ni];
    }
#pragma unroll
    for (int mi = 0; mi < 4; ++mi)
#pragma unroll
        for (int ni = 0; ni < 2; ++ni)
            acc[mi][ni] = __builtin_amdgcn_mfma_f32_16x16x32_bf16(bfr[ni], af[mi], acc[mi][ni], 0, 0, 0);

#pragma unroll
    for (int mi = 0; mi < 4; ++mi)
#pragma unroll
        for (int ni = 0; ni < 2; ++ni)
            *(f32x4*)&ct[mi * 16 + r16][w * 32 + ni * 16 + kq * 4] = acc[mi][ni];
    __syncthreads();
    f32x4 bv = *(const f32x4*)(bias + gcol);
    f32x4 zz = {0.f, 0.f, 0.f, 0.f};
#pragma unroll
    for (int it = 0; it < 8; ++it) {
        int r = it * 8 + r0;
        int orv = os[r];
        if (orv >= 0) {
            f32x4 v = *(f32x4*)&ct[r][cc];
            f32x4 oo;
            oo[0] = v[0] + bv[0]; oo[1] = v[1] + bv[1];
            oo[2] = v[2] + bv[2]; oo[3] = v[3] + bv[3];
            *(f32x4*)(out + OUT_PREDS + (long)orv * V_ + gcol) = oo;
        } else {
            int row = -orv - 1;
            *(f32x4*)(out + OUT_PREDS + (long)row * V_ + gcol) = zz;
        }
    }
}

extern "C" void kernel_launch(void* const* d_in, const int* in_sizes, int n_in,
                              void* d_out, int out_size, void* d_ws, size_t ws_size,
                              hipStream_t stream)
{
    const float* enc       = (const float*)d_in[0];
    const int*   caps      = (const int*)  d_in[1];
    const int*   caplen    = (const int*)  d_in[2];
    const float* emb       = (const float*)d_in[3];
    const float* W_enc_att = (const float*)d_in[4];
    const float* b_enc_att = (const float*)d_in[5];
    const float* W_dec_att = (const float*)d_in[6];
    const float* b_dec_att = (const float*)d_in[7];
    const float* W_full    = (const float*)d_in[8];
    // d_in[9] = b_full (softmax-invariant, unused)
    const float* W_ih      = (const float*)d_in[10];
    const float* b_ih      = (const float*)d_in[11];
    const float* W_hh      = (const float*)d_in[12];
    const float* b_hh      = (const float*)d_in[13];
    const float* g_h       = (const float*)d_in[14];
    const float* be_h      = (const float*)d_in[15];
    const float* g_c       = (const float*)d_in[16];
    const float* be_c      = (const float*)d_in[17];
    const float* W_init_h  = (const float*)d_in[18];
    const float* b_init_h  = (const float*)d_in[19];
    const float* W_init_c  = (const float*)d_in[20];
    const float* b_init_c  = (const float*)d_in[21];
    const float* W_beta    = (const float*)d_in[22];
    const float* b_beta    = (const float*)d_in[23];
    const float* W_fc      = (const float*)d_in[24];
    const float* b_fc      = (const float*)d_in[25];
    float* out = (float*)d_out;

    char* w = (char*)d_ws;
    auto alloc = [&](size_t bytes) { char* p = w; w += (bytes + 255) & ~(size_t)255; return p; };
    int*   order_i  = (int*)  alloc(B_ * 4);
    int*   declen_i = (int*)  alloc(B_ * 4);
    int*   caps_i   = (int*)  alloc(B_ * L_ * 4);
    int*   rmap     = (int*)  alloc(2048 * 4);
    int*   orow     = (int*)  alloc(2048 * 4);
    int*   mact     = (int*)  alloc(256);
    bf16*  enc_s    = (bf16*) alloc((size_t)B_ * P_ * ENC_ * 2);
    bf16*  enc_pk   = (bf16*) alloc((size_t)B_ * P_ * ENC_ * 2);
    bf16*  mean_b   = (bf16*) alloc((size_t)B_ * ENC_ * 2);
    bf16*  att1_b   = (bf16*) alloc((size_t)B_ * P_ * 512 * 2);
    float* pi       = (float*)alloc((size_t)B_ * 1024 * 4);
    float* cbuf     = (float*)alloc((size_t)B_ * 512 * 4);
    bf16*  xh       = (bf16*) alloc((size_t)B_ * 3072 * 2);
    float* att2g    = (float*)alloc((size_t)B_ * 2560 * 4);
    float* gp       = (float*)alloc((size_t)8 * B_ * 2048 * 4);
    bf16*  hseq     = (bf16*) alloc((size_t)T_ * B_ * 512 * 2);
    bf16*  Apk      = (bf16*) alloc((size_t)31 * 32768 * 2);
    bf16*  W_inh_b  = (bf16*) alloc((size_t)512 * 2048 * 2);
    bf16*  W_inc_b  = (bf16*) alloc((size_t)512 * 2048 * 2);
    bf16*  Wab_rm   = (bf16*) alloc((size_t)2560 * 512 * 2);    // [W_dec;W_beta] row-major
    bf16*  Wenc_pk  = (bf16*) alloc((size_t)512 * 2048 * 2);    // W_enc packed
    bf16*  Wg_pk    = (bf16*) alloc((size_t)2048 * 3072 * 2);   // [W_ih;W_hh] packed
    bf16*  Wfc_pk   = (bf16*) alloc((size_t)32000 * 512 * 2);   // W_fc packed

    k_order<<<1, B_, 0, stream>>>(caplen, caps, order_i, declen_i, caps_i, out, rmap, orow, mact);
    k_cvt_enc<<<12544, 256, 0, stream>>>(enc, order_i, enc_s, enc_pk);
    k_meanb<<<dim3(B_, 8), 256, 0, stream>>>(enc_s, mean_b);

    // plain converts: init weights + [W_dec;W_beta] row-major concat
    CvtSegs cs;
    const float* srcs[4] = {W_init_h, W_init_c, W_dec_att, W_beta};
    bf16* dsts[4] = {W_inh_b, W_inc_b, Wab_rm, Wab_rm + (size_t)512 * 512};
    long ns[4] = {512L*2048, 512L*2048, 512L*512, 2048L*512};
    long cum = 0;
    for (int i = 0; i < 4; ++i) { cs.s[i] = srcs[i]; cs.d[i] = dsts[i]; cs.cum[i] = cum; cum += ns[i]; }
    cs.cum[4] = cum;
    k_cvt_all<<<(int)((cum / 8 + 255) / 256), 256, 0, stream>>>(cs);

    // fragment-packed weights
    k_packB<0><<<32, 256, 0, stream>>>(W_enc_att, nullptr, Wenc_pk, 2048, 0);
    k_packB<2><<<128, 256, 0, stream>>>(W_ih, W_hh, Wg_pk, 3072, 2560);
    k_packB<0><<<2000, 256, 0, stream>>>(W_fc, nullptr, Wfc_pk, 512, 0);

    // init: [h|c] = mean_b @ [W_init_h|W_init_c]^T (N-split), then LN + att2g(t=0)
    k_mgemm<4, 1, 0, 0, 0, 0><<<dim3(1, 8, 1), 256, 0, stream>>>(mean_b, 2048, W_inh_b, W_inc_b,
        nullptr, pi, nullptr, 1024, 2048, 1, 512, 64);
    k_initln<<<B_, 512, 0, stream>>>(pi, b_init_h, b_init_c, g_h, be_h, g_c, be_c,
        Wab_rm, xh, cbuf, att2g);

    // att1 = enc_pk @ Wenc_pk^T + b -> bf16 [12544][512]; MI=4, 784 blocks XCD-chunked
    k_mgemm<4, 0, 1, 1, 1, 1><<<784, 256, 0, stream>>>(enc_pk, 0, Wenc_pk, nullptr,
        b_enc_att, nullptr, att1_b, 512, 2048, 1, 0, 12544);

    for (int t = 0; t < T_; ++t) {
        k_attn<<<128, 512, 0, stream>>>(att2g, b_dec_att, b_beta, W_full, att1_b, enc_s,
            caps_i, declen_i, emb, xh, out, t);
        // gates = xh @ packed[W_ih;W_hh]^T (split-K S=8)
        k_mgemm<4, 0, 0, 0, 1, 0><<<dim3(1, 16, 8), 256, 0, stream>>>(xh, 3072, Wg_pk, nullptr,
            nullptr, gp, nullptr, 2048, 3072, 8, 0, 64);
        // LSTM + LN + state + hseq + next-step att2|gate matvec (fused)
        k_lstm<<<B_, 512, 0, stream>>>(gp, b_ih, b_hh, g_h, be_h, g_c, be_c,
            Wab_rm, xh, cbuf, hseq, att2g, declen_i, t);
    }

    // pack hseq (rmap gather) then preds with zero-fill merged
    k_packA<<<31, 256, 0, stream>>>(hseq, rmap, Apk);
    k_preds<<<7750, 256, 0, stream>>>(Apk, Wfc_pk, b_fc, orow, mact, out);
}

// Round 13
// 2087.724 us; speedup vs baseline: 3.5208x; 3.5208x over previous
//
#include <hip/hip_runtime.h>
#include <cfloat>
#include <math.h>

#define B_ 64
#define P_ 196
#define ENC_ 2048
#define D_ 512
#define V_ 32000
#define L_ 32
#define T_ 31

// flat f32 output layout (reference return order)
#define OUT_PREDS 0L
#define OUT_CAPS  63488000L              // 64*31*32000
#define OUT_DECL  63490048L              // +64*32
#define OUT_ALPH  63490112L              // +64
#define OUT_ORDER 63878976L              // +64*31*196

typedef __bf16 bf16;
typedef __bf16 bf16x8 __attribute__((ext_vector_type(8)));
typedef __bf16 bf16x4 __attribute__((ext_vector_type(4)));
typedef __bf16 bf16x2 __attribute__((ext_vector_type(2)));
typedef float  f32x4  __attribute__((ext_vector_type(4)));

static __device__ __forceinline__ float sigmoidf_(float x) { return 1.f / (1.f + __expf(-x)); }

// ------- sort, caps gather, scalar outputs, full-row map (active + inactive) -------
__global__ void k_order(const int* __restrict__ cap_len, const int* __restrict__ caps,
                        int* __restrict__ order_i, int* __restrict__ declen_i,
                        int* __restrict__ caps_i, float* __restrict__ out,
                        int* __restrict__ rmap, int* __restrict__ orow, int* __restrict__ mact)
{
    __shared__ int len_s[B_], dl_s[B_];
    __shared__ int Msh;
    int tid = threadIdx.x;
    len_s[tid] = cap_len[tid];
    __syncthreads();
    int li = len_s[tid];
    int pos = 0;
    for (int j = 0; j < B_; ++j) {
        int lj = len_s[j];
        pos += (lj > li) || (lj == li && j < tid);   // stable descending rank
    }
    order_i[pos]  = tid;
    declen_i[pos] = li - 1;
    dl_s[pos]     = li - 1;
    out[OUT_ORDER + pos] = (float)tid;
    out[OUT_DECL  + pos] = (float)(li - 1);
    for (int l = 0; l < L_; ++l) {
        int tok = caps[tid * L_ + l];
        caps_i[pos * L_ + l] = tok;
        out[OUT_CAPS + pos * L_ + l] = (float)tok;
    }
    __syncthreads();
    int p = tid;
    int off = 0;
    for (int j = 0; j < p; ++j) off += dl_s[j];
    int dl = dl_s[p];
    if (p == B_ - 1) { Msh = off + dl; mact[0] = off + dl; }
    __syncthreads();
    // active slots [off, off+dl): GEMM rows; inactive slots: zero rows (sign-encoded)
    for (int tt = 0; tt < dl; ++tt) {
        rmap[off + tt] = tt * B_ + p;
        orow[off + tt] = p * T_ + tt;
    }
    int ibase = Msh + p * T_ - off;
    for (int tt = dl; tt < T_; ++tt) {
        rmap[ibase + (tt - dl)] = 0;
        orow[ibase + (tt - dl)] = -(p * T_ + tt) - 1;
    }
}

// ---------------- merged f32 -> bf16 convert (plain row-major mats) ----------------
struct CvtSegs { const float* s[2]; bf16* d[2]; long cum[3]; };
__global__ __launch_bounds__(256) void k_cvt_all(CvtSegs cs)
{
    long i8 = ((long)blockIdx.x * 256 + threadIdx.x) * 8;
    if (i8 >= cs.cum[2]) return;
    int k = 0;
    while (i8 >= cs.cum[k + 1]) ++k;
    long loc = i8 - cs.cum[k];
    const float* src = cs.s[k] + loc;
    float4 a = *(const float4*)(src);
    float4 b = *(const float4*)(src + 4);
    bf16x8 v;
    v[0]=(bf16)a.x; v[1]=(bf16)a.y; v[2]=(bf16)a.z; v[3]=(bf16)a.w;
    v[4]=(bf16)b.x; v[5]=(bf16)b.y; v[6]=(bf16)b.z; v[7]=(bf16)b.w;
    *(bf16x8*)(cs.d[k] + loc) = v;
}

// ------- pack f32 weights -> MFMA-fragment-ordered bf16 -------
// layout: dst[(n>>4)*Kv*16 + (k>>3)*128 + (n&15)*8 + (k&7)]
// MODE 0: plain s1[N][Kv]; 1: N-split at Nsp (both row-len Kv); 2: K-split at Ksp
template<int MODE>
__global__ __launch_bounds__(256)
void k_packB(const float* __restrict__ s1, const float* __restrict__ s2,
             bf16* __restrict__ dst, int Kv, int Nsp, int Ksp)
{
    const int ntile = blockIdx.x, tid = threadIdx.x;
    long tbase = (long)ntile * Kv * 16;
    const int groups = Kv * 2;                    // (Kv/8) * 16
    for (int g = tid; g < groups; g += 256) {
        int kkq = g >> 4, r16 = g & 15;
        int n = ntile * 16 + r16, k0 = kkq * 8;
        const float* src;
        if (MODE == 0)      src = s1 + (long)n * Kv + k0;
        else if (MODE == 1) src = (n < Nsp) ? s1 + (long)n * Kv + k0
                                            : s2 + (long)(n - Nsp) * Kv + k0;
        else                src = (k0 < Ksp) ? s1 + (long)n * Ksp + k0
                                             : s2 + (long)n * (Kv - Ksp) + (k0 - Ksp);
        float4 a = *(const float4*)src;
        float4 b = *(const float4*)(src + 4);
        bf16x8 v;
        v[0]=(bf16)a.x; v[1]=(bf16)a.y; v[2]=(bf16)a.z; v[3]=(bf16)a.w;
        v[4]=(bf16)b.x; v[5]=(bf16)b.y; v[6]=(bf16)b.z; v[7]=(bf16)b.w;
        *(bf16x8*)(dst + tbase + (long)kkq * 128 + r16 * 8) = v;
    }
}

// ------- pack hseq (gathered by rmap) -> fragment order for preds A -------
__global__ __launch_bounds__(256)
void k_packA(const bf16* __restrict__ hseq, const int* __restrict__ rmap, bf16* __restrict__ dst)
{
    const int mt = blockIdx.x, tid = threadIdx.x;
    long tbase = (long)mt * 32768;
    for (int g = tid; g < 4096; g += 256) {       // mi(4) x kkq(64) x r16(16)
        int mi = g >> 10, rem = g & 1023, kkq = rem >> 4, r16 = rem & 15;
        int row = rmap[mt * 64 + mi * 16 + r16];
        bf16x8 v = *(const bf16x8*)(hseq + (long)row * 512 + kkq * 8);
        *(bf16x8*)(dst + tbase + mi * 8192 + (long)kkq * 128 + r16 * 8) = v;
    }
}

// --- enc gather-by-order -> bf16, DUAL write: row-major enc_s + fragment enc_pk ---
__global__ __launch_bounds__(256) void k_cvt_enc(const float* __restrict__ enc,
                                                 const int* __restrict__ order_i,
                                                 bf16* __restrict__ enc_s,
                                                 bf16* __restrict__ enc_pk)
{
    long i = ((long)blockIdx.x * 256 + threadIdx.x) * 8;
    int r = (int)(i >> 11);                 // global sorted row (b*196+p)
    int k0 = (int)(i & 2047);
    int b = (int)(i / ((long)P_ * ENC_));
    long rem = i - (long)b * P_ * ENC_;
    const float* src = enc + (long)order_i[b] * P_ * ENC_ + rem;
    float4 a = *(const float4*)(src);
    float4 c = *(const float4*)(src + 4);
    bf16x8 v;
    v[0]=(bf16)a.x; v[1]=(bf16)a.y; v[2]=(bf16)a.z; v[3]=(bf16)a.w;
    v[4]=(bf16)c.x; v[5]=(bf16)c.y; v[6]=(bf16)c.z; v[7]=(bf16)c.w;
    *(bf16x8*)(enc_s + i) = v;
    *(bf16x8*)(enc_pk + (long)(r >> 4) * 32768 + (long)(k0 >> 3) * 128 + (r & 15) * 8) = v;
}

// ---------------- mean over pixels ----------------
__global__ __launch_bounds__(256) void k_meanb(const bf16* __restrict__ enc_s, bf16* __restrict__ mean_b)
{
    int b = blockIdx.x, col = blockIdx.y * 256 + threadIdx.x;
    float s = 0.f;
    const bf16* eb = enc_s + (long)b * P_ * ENC_ + col;
    for (int p = 0; p < P_; ++p) s += (float)eb[(long)p * ENC_];
    mean_b[(long)b * ENC_ + col] = (bf16)(s * (1.f / (float)P_));
}

// ---------------- MFMA GEMM: C[M][N] = A[M][K](bf16) * B[N][K]^T(bf16) ------
// 256 thr = 4 waves; tile (MI*16) x 128; swapped-operand mfma -> dwordx4 stores.
// PK=1: B fragment-packed. PA=1: A fragment-packed (row-tiles of 16).
// FUSE: 0=single B, 1=N-split at Nsp. EPI: 0=RAW f32 slot z, 1=bf16 +bias.
// SWZ:  0=3D grid; 1=att1 784 blocks XCD-chunked mt-major
template<int MI, int FUSE, int EPI, int SWZ, int PK, int PA>
__global__ void __launch_bounds__(256)
k_mgemm(const bf16* __restrict__ A, long lda,
        const bf16* __restrict__ B1, const bf16* __restrict__ B2,
        const float* __restrict__ bias,
        float* __restrict__ Cf, bf16* __restrict__ Cb,
        int N, int K, int kspl, int Nsp, int Mtot)
{
    const int tid = threadIdx.x;
    const int lane = tid & 63, w = tid >> 6;
    int mt, nt, z;
    if (SWZ == 0) { mt = blockIdx.x; nt = blockIdx.y; z = blockIdx.z; }
    else          { int o = blockIdx.x; int wg = (o & 7) * 98 + (o >> 3);
                    mt = wg >> 2; nt = wg & 3; z = 0; }
    const int krange = K / kspl;
    const int k0 = z * krange, k1 = k0 + krange;
    const int r16 = lane & 15, kq = lane >> 4;
    const int koff = kq * 8;

    const bf16* Ap[MI];
#pragma unroll
    for (int mi = 0; mi < MI; ++mi) {
        if (PA) Ap[mi] = A + (long)(mt * MI + mi) * ((long)K * 16) + kq * 128 + r16 * 8;
        else    Ap[mi] = A + (long)(mt * (MI * 16) + mi * 16 + r16) * lda + koff;
    }
    const int ncol0 = nt * 128 + w * 32;

    const bf16* Bp[2];
#pragma unroll
    for (int ni = 0; ni < 2; ++ni) {
        if (PK) {
            Bp[ni] = B1 + (long)((ncol0 + ni * 16) >> 4) * ((long)K * 16) + kq * 128 + r16 * 8;
        } else {
            int n = ncol0 + ni * 16 + r16;
            if (FUSE == 1)
                Bp[ni] = (n < Nsp) ? B1 + (long)n * K + koff
                                   : B2 + (long)(n - Nsp) * K + koff;
            else
                Bp[ni] = B1 + (long)n * K + koff;
        }
    }

    auto loadA = [&](int kk, bf16x8* dst) {
#pragma unroll
        for (int mi = 0; mi < MI; ++mi)
            dst[mi] = PA ? *(const bf16x8*)(Ap[mi] + (long)kk * 16)
                         : *(const bf16x8*)(Ap[mi] + kk);
    };
    auto loadB = [&](int kk, bf16x8* dst) {
#pragma unroll
        for (int ni = 0; ni < 2; ++ni)
            dst[ni] = PK ? *(const bf16x8*)(Bp[ni] + (long)kk * 16)
                         : *(const bf16x8*)(Bp[ni] + kk);
    };

    f32x4 acc[MI][2] = {};
    bf16x8 af[MI], bfr[2];
    loadA(k0, af); loadB(k0, bfr);
    for (int kk = k0 + 32; kk < k1; kk += 32) {
        bf16x8 af2[MI], bf2[2];
        loadA(kk, af2); loadB(kk, bf2);
#pragma unroll
        for (int mi = 0; mi < MI; ++mi)
#pragma unroll
            for (int ni = 0; ni < 2; ++ni)
                acc[mi][ni] = __builtin_amdgcn_mfma_f32_16x16x32_bf16(bfr[ni], af[mi], acc[mi][ni], 0, 0, 0);
#pragma unroll
        for (int mi = 0; mi < MI; ++mi) af[mi] = af2[mi];
#pragma unroll
        for (int ni = 0; ni < 2; ++ni) bfr[ni] = bf2[ni];
    }
#pragma unroll
    for (int mi = 0; mi < MI; ++mi)
#pragma unroll
        for (int ni = 0; ni < 2; ++ni)
            acc[mi][ni] = __builtin_amdgcn_mfma_f32_16x16x32_bf16(bfr[ni], af[mi], acc[mi][ni], 0, 0, 0);

#pragma unroll
    for (int mi = 0; mi < MI; ++mi) {
        const int row = mt * (MI * 16) + mi * 16 + r16;
#pragma unroll
        for (int ni = 0; ni < 2; ++ni) {
            const int col = ncol0 + ni * 16 + kq * 4;
            f32x4 v = acc[mi][ni];
            if (EPI == 0) {
                *(f32x4*)(Cf + (long)z * Mtot * N + (long)row * N + col) = v;
            } else {
                f32x4 bv = *(const f32x4*)(bias + col);
                bf16x4 o;
                o[0]=(bf16)(v[0]+bv[0]); o[1]=(bf16)(v[1]+bv[1]);
                o[2]=(bf16)(v[2]+bv[2]); o[3]=(bf16)(v[3]+bv[3]);
                *(bf16x4*)(Cb + (long)row * N + col) = o;
            }
        }
    }
}

// ---------------- init h,c = LN(mean_enc @ W^T + b) ----------------
__global__ __launch_bounds__(512)
void k_initln(const float* __restrict__ pi,
              const float* __restrict__ b_h, const float* __restrict__ b_c,
              const float* __restrict__ g_h, const float* __restrict__ be_h,
              const float* __restrict__ g_c, const float* __restrict__ be_c,
              bf16* __restrict__ xh, float* __restrict__ cbuf)
{
    int b = blockIdx.x, d = threadIdx.x;
    float yh = pi[(long)b * 1024 + d]       + b_h[d];
    float yc = pi[(long)b * 1024 + 512 + d] + b_c[d];
    __shared__ float r1[512], r2[512], r3[512], r4[512];
    r1[d] = yh; r2[d] = yh * yh; r3[d] = yc; r4[d] = yc * yc;
    __syncthreads();
    for (int s = 256; s > 0; s >>= 1) {
        if (d < s) { r1[d]+=r1[d+s]; r2[d]+=r2[d+s]; r3[d]+=r3[d+s]; r4[d]+=r4[d+s]; }
        __syncthreads();
    }
    float mh = r1[0] * (1.f/512.f), vh = r2[0] * (1.f/512.f) - mh*mh;
    float mc = r3[0] * (1.f/512.f), vc = r4[0] * (1.f/512.f) - mc*mc;
    float hln = (yh - mh) * rsqrtf(vh + 1e-5f) * g_h[d] + be_h[d];
    float cln = (yc - mc) * rsqrtf(vc + 1e-5f) * g_c[d] + be_c[d];
    xh[(long)b * 3072 + 2560 + d] = (bf16)hln;
    cbuf[(long)b * 512 + d] = cln;
}

// ------- fused attention: alpha + awe*gate + emb; 128 blocks = (b, seg of 1024 cols) -------
__global__ __launch_bounds__(512)
void k_attn(const float* __restrict__ att2gate, const float* __restrict__ b_dec,
            const float* __restrict__ b_beta, const float* __restrict__ Wfull,
            const bf16* __restrict__ att1_b, const bf16* __restrict__ enc_s,
            const int* __restrict__ caps_i, const int* __restrict__ declen_i,
            const float* __restrict__ emb,
            bf16* __restrict__ xh, float* __restrict__ out, int t)
{
    const int b = blockIdx.x >> 1, seg = blockIdx.x & 1, tid = threadIdx.x;
    if (t >= declen_i[b]) {
        if (seg == 1 && tid < P_) out[OUT_ALPH + ((long)b * T_ + t) * P_ + tid] = 0.f;
        return;
    }
    __shared__ float att2s[512], wf[512], red[512], alp[P_];
    {
        float s = b_dec[tid];
#pragma unroll
        for (int zz = 0; zz < 4; ++zz) s += att2gate[((long)zz * 64 + b) * 2560 + tid];
        att2s[tid] = s;
        wf[tid] = Wfull[tid];
    }
    __syncthreads();
    float ev = -FLT_MAX;
    if (tid < P_) {
        const bf16* ar = att1_b + ((long)b * P_ + tid) * 512;
        float acc = 0.f;
        for (int a0 = 0; a0 < 512; a0 += 8) {
            bf16x8 v = *(const bf16x8*)(ar + a0);
#pragma unroll
            for (int j = 0; j < 8; ++j)
                acc += fmaxf((float)v[j] + att2s[a0 + j], 0.f) * wf[a0 + j];
        }
        ev = acc;   // + b_full: softmax-invariant
    }
    red[tid] = ev;
    __syncthreads();
    for (int s = 256; s > 0; s >>= 1) { if (tid < s) red[tid] = fmaxf(red[tid], red[tid + s]); __syncthreads(); }
    float mx = red[0];
    __syncthreads();
    float ex = (tid < P_) ? __expf(ev - mx) : 0.f;
    red[tid] = ex;
    __syncthreads();
    for (int s = 256; s > 0; s >>= 1) { if (tid < s) red[tid] += red[tid + s]; __syncthreads(); }
    float inv = 1.f / red[0];
    if (tid < P_) alp[tid] = ex * inv;
    __syncthreads();
    if (seg == 1 && tid < P_)
        out[OUT_ALPH + ((long)b * T_ + t) * P_ + tid] = alp[tid];
    // awe for this 1024-col segment (bf16x2 per thread)
    const int c0 = seg * 1024 + tid * 2;
    const bf16* eb = enc_s + (long)b * P_ * ENC_ + c0;
    float a0 = 0.f, a1 = 0.f;
#pragma unroll 4
    for (int p = 0; p < P_; ++p) {
        bf16x2 v = *(const bf16x2*)(eb + (long)p * ENC_);
        float al = alp[p];
        a0 += al * (float)v[0]; a1 += al * (float)v[1];
    }
    float g0 = b_beta[c0], g1 = b_beta[c0 + 1];
#pragma unroll
    for (int zz = 0; zz < 4; ++zz) {
        const float* gs = att2gate + ((long)zz * 64 + b) * 2560 + 512 + c0;
        g0 += gs[0]; g1 += gs[1];
    }
    bf16x2 o;
    o[0] = (bf16)(a0 * sigmoidf_(g0));
    o[1] = (bf16)(a1 * sigmoidf_(g1));
    *(bf16x2*)(xh + (long)b * 3072 + 512 + c0) = o;
    if (seg == 0) {
        int tok = caps_i[b * L_ + t];
        xh[(long)b * 3072 + tid] = (bf16)emb[(long)tok * 512 + tid];
    }
}

// -------- LSTM + 2x LN + state update + hseq record --------
__global__ __launch_bounds__(512)
void k_lstm(const float* __restrict__ gp, const float* __restrict__ b_ih, const float* __restrict__ b_hh,
            const float* __restrict__ g_h, const float* __restrict__ be_h,
            const float* __restrict__ g_c, const float* __restrict__ be_c,
            bf16* __restrict__ xh, float* __restrict__ cbuf, bf16* __restrict__ hseq,
            const int* __restrict__ declen_i, int t)
{
    int b = blockIdx.x, d = threadIdx.x;
    if (t >= declen_i[b]) return;
    float iv = b_ih[d]        + b_hh[d];
    float fv = b_ih[512 + d]  + b_hh[512 + d];
    float gv = b_ih[1024 + d] + b_hh[1024 + d];
    float ov = b_ih[1536 + d] + b_hh[1536 + d];
#pragma unroll
    for (int s = 0; s < 8; ++s) {
        const float* gs = gp + ((long)s * B_ + b) * 2048;
        iv += gs[d]; fv += gs[512 + d]; gv += gs[1024 + d]; ov += gs[1536 + d];
    }
    float cn = sigmoidf_(fv) * cbuf[(long)b * 512 + d] + sigmoidf_(iv) * tanhf(gv);
    float hn = sigmoidf_(ov) * tanhf(cn);
    __shared__ float r1[512], r2[512], r3[512], r4[512];
    r1[d] = hn; r2[d] = hn * hn; r3[d] = cn; r4[d] = cn * cn;
    __syncthreads();
    for (int s = 256; s > 0; s >>= 1) {
        if (d < s) { r1[d]+=r1[d+s]; r2[d]+=r2[d+s]; r3[d]+=r3[d+s]; r4[d]+=r4[d+s]; }
        __syncthreads();
    }
    float mh = r1[0] * (1.f/512.f), vh = r2[0] * (1.f/512.f) - mh*mh;
    float mc = r3[0] * (1.f/512.f), vc = r4[0] * (1.f/512.f) - mc*mc;
    float hln = (hn - mh) * rsqrtf(vh + 1e-5f) * g_h[d] + be_h[d];
    float cln = (cn - mc) * rsqrtf(vc + 1e-5f) * g_c[d] + be_c[d];
    bf16 hv = (bf16)hln;
    xh[(long)b * 3072 + 2560 + d] = hv;
    hseq[((long)t * B_ + b) * 512 + d] = hv;
    cbuf[(long)b * 512 + d] = cln;
}

// -------- preds: packed A/B fragment loads; zero-fill merged (sign-encoded orow) --------
__global__ __launch_bounds__(256)
void k_preds(const bf16* __restrict__ Apk, const bf16* __restrict__ Bpk,
             const float* __restrict__ bias, const int* __restrict__ orow,
             const int* __restrict__ mact, float* __restrict__ out)
{
    int o = blockIdx.x; int xcd = o & 7;
    int base = xcd < 6 ? xcd * 969 : 5814 + (xcd - 6) * 968;
    int wg = base + (o >> 3);
    int nt = wg / 31, mt = wg - 31 * nt;
    __shared__ int os[64];
    __shared__ __align__(16) float ct[64][132];
    const int tid = threadIdx.x, lane = tid & 63, w = tid >> 6;
    const int r16 = lane & 15, kq = lane >> 4;
    if (tid < 64) os[tid] = orow[mt * 64 + tid];
    __syncthreads();
    const int r0 = tid >> 5, cc = (tid & 31) * 4;
    const int gcol = nt * 128 + cc;
    if (mt * 64 >= mact[0]) {          // pure-inactive tile: zero-fill only
        f32x4 zz = {0.f, 0.f, 0.f, 0.f};
#pragma unroll
        for (int it = 0; it < 8; ++it) {
            int r = it * 8 + r0;
            int row = -os[r] - 1;
            *(f32x4*)(out + OUT_PREDS + (long)row * V_ + gcol) = zz;
        }
        return;
    }
    const bf16* Ap[4];
#pragma unroll
    for (int mi = 0; mi < 4; ++mi)
        Ap[mi] = Apk + (long)mt * 32768 + mi * 8192 + kq * 128 + r16 * 8;
    const bf16* Bp[2];
#pragma unroll
    for (int ni = 0; ni < 2; ++ni)
        Bp[ni] = Bpk + (long)((nt * 128 + w * 32 + ni * 16) >> 4) * 8192 + kq * 128 + r16 * 8;

    f32x4 acc[4][2] = {};
    bf16x8 af[4], bfr[2];
#pragma unroll
    for (int mi = 0; mi < 4; ++mi) af[mi] = *(const bf16x8*)(Ap[mi]);
#pragma unroll
    for (int ni = 0; ni < 2; ++ni) bfr[ni] = *(const bf16x8*)(Bp[ni]);
    for (int kk = 32; kk < 512; kk += 32) {
        bf16x8 af2[4], bf2[2];
#pragma unroll
        for (int mi = 0; mi < 4; ++mi) af2[mi] = *(const bf16x8*)(Ap[mi] + kk * 16);
#pragma unroll
        for (int ni = 0; ni < 2; ++ni) bf2[ni] = *(const bf16x8*)(Bp[ni] + kk * 16);
#pragma unroll
        for (int mi = 0; mi < 4; ++mi)
#pragma unroll
            for (int ni = 0; ni < 2; ++ni)
                acc[mi][ni] = __builtin_amdgcn_mfma_f32_16x16x32_bf16(bfr[ni], af[mi], acc[mi][ni], 0, 0, 0);
#pragma unroll
        for (int mi = 0; mi < 4; ++mi) af[mi] = af2[mi];
#pragma unroll
        for (int ni = 0; ni < 2; ++ni) bfr[ni] = bf2[ni];
    }
#pragma unroll
    for (int mi = 0; mi < 4; ++mi)
#pragma unroll
        for (int ni = 0; ni < 2; ++ni)
            acc[mi][ni] = __builtin_amdgcn_mfma_f32_16x16x32_bf16(bfr[ni], af[mi], acc[mi][ni], 0, 0, 0);

#pragma unroll
    for (int mi = 0; mi < 4; ++mi)
#pragma unroll
        for (int ni = 0; ni < 2; ++ni)
            *(f32x4*)&ct[mi * 16 + r16][w * 32 + ni * 16 + kq * 4] = acc[mi][ni];
    __syncthreads();
    f32x4 bv = *(const f32x4*)(bias + gcol);
    f32x4 zz = {0.f, 0.f, 0.f, 0.f};
#pragma unroll
    for (int it = 0; it < 8; ++it) {
        int r = it * 8 + r0;
        int orv = os[r];
        if (orv >= 0) {
            f32x4 v = *(f32x4*)&ct[r][cc];
            f32x4 oo;
            oo[0] = v[0] + bv[0]; oo[1] = v[1] + bv[1];
            oo[2] = v[2] + bv[2]; oo[3] = v[3] + bv[3];
            *(f32x4*)(out + OUT_PREDS + (long)orv * V_ + gcol) = oo;
        } else {
            int row = -orv - 1;
            *(f32x4*)(out + OUT_PREDS + (long)row * V_ + gcol) = zz;
        }
    }
}

extern "C" void kernel_launch(void* const* d_in, const int* in_sizes, int n_in,
                              void* d_out, int out_size, void* d_ws, size_t ws_size,
                              hipStream_t stream)
{
    const float* enc       = (const float*)d_in[0];
    const int*   caps      = (const int*)  d_in[1];
    const int*   caplen    = (const int*)  d_in[2];
    const float* emb       = (const float*)d_in[3];
    const float* W_enc_att = (const float*)d_in[4];
    const float* b_enc_att = (const float*)d_in[5];
    const float* W_dec_att = (const float*)d_in[6];
    const float* b_dec_att = (const float*)d_in[7];
    const float* W_full    = (const float*)d_in[8];
    // d_in[9] = b_full (softmax-invariant, unused)
    const float* W_ih      = (const float*)d_in[10];
    const float* b_ih      = (const float*)d_in[11];
    const float* W_hh      = (const float*)d_in[12];
    const float* b_hh      = (const float*)d_in[13];
    const float* g_h       = (const float*)d_in[14];
    const float* be_h      = (const float*)d_in[15];
    const float* g_c       = (const float*)d_in[16];
    const float* be_c      = (const float*)d_in[17];
    const float* W_init_h  = (const float*)d_in[18];
    const float* b_init_h  = (const float*)d_in[19];
    const float* W_init_c  = (const float*)d_in[20];
    const float* b_init_c  = (const float*)d_in[21];
    const float* W_beta    = (const float*)d_in[22];
    const float* b_beta    = (const float*)d_in[23];
    const float* W_fc      = (const float*)d_in[24];
    const float* b_fc      = (const float*)d_in[25];
    float* out = (float*)d_out;

    char* w = (char*)d_ws;
    auto alloc = [&](size_t bytes) { char* p = w; w += (bytes + 255) & ~(size_t)255; return p; };
    int*   order_i  = (int*)  alloc(B_ * 4);
    int*   declen_i = (int*)  alloc(B_ * 4);
    int*   caps_i   = (int*)  alloc(B_ * L_ * 4);
    int*   rmap     = (int*)  alloc(2048 * 4);
    int*   orow     = (int*)  alloc(2048 * 4);
    int*   mact     = (int*)  alloc(256);
    bf16*  enc_s    = (bf16*) alloc((size_t)B_ * P_ * ENC_ * 2);
    bf16*  enc_pk   = (bf16*) alloc((size_t)B_ * P_ * ENC_ * 2);
    bf16*  mean_b   = (bf16*) alloc((size_t)B_ * ENC_ * 2);
    bf16*  att1_b   = (bf16*) alloc((size_t)B_ * P_ * 512 * 2);
    float* pi       = (float*)alloc((size_t)B_ * 1024 * 4);
    float* cbuf     = (float*)alloc((size_t)B_ * 512 * 4);
    bf16*  xh       = (bf16*) alloc((size_t)B_ * 3072 * 2);
    float* att2gate = (float*)alloc((size_t)4 * B_ * 2560 * 4);
    float* gp       = (float*)alloc((size_t)8 * B_ * 2048 * 4);
    bf16*  hseq     = (bf16*) alloc((size_t)T_ * B_ * 512 * 2);
    bf16*  Apk      = (bf16*) alloc((size_t)31 * 32768 * 2);
    bf16*  W_inh_b  = (bf16*) alloc((size_t)512 * 2048 * 2);
    bf16*  W_inc_b  = (bf16*) alloc((size_t)512 * 2048 * 2);
    bf16*  Wenc_pk  = (bf16*) alloc((size_t)512 * 2048 * 2);    // W_enc packed
    bf16*  Wab_pk   = (bf16*) alloc((size_t)2560 * 512 * 2);    // [W_dec|W_beta] packed
    bf16*  Wg_pk    = (bf16*) alloc((size_t)2048 * 3072 * 2);   // [W_ih;W_hh] packed
    bf16*  Wfc_pk   = (bf16*) alloc((size_t)32000 * 512 * 2);   // W_fc packed

    k_order<<<1, B_, 0, stream>>>(caplen, caps, order_i, declen_i, caps_i, out, rmap, orow, mact);
    k_cvt_enc<<<12544, 256, 0, stream>>>(enc, order_i, enc_s, enc_pk);
    k_meanb<<<dim3(B_, 8), 256, 0, stream>>>(enc_s, mean_b);

    // plain converts (init weights only)
    CvtSegs cs;
    const float* srcs[2] = {W_init_h, W_init_c};
    bf16* dsts[2] = {W_inh_b, W_inc_b};
    long ns[2] = {512L*2048, 512L*2048};
    long cum = 0;
    for (int i = 0; i < 2; ++i) { cs.s[i] = srcs[i]; cs.d[i] = dsts[i]; cs.cum[i] = cum; cum += ns[i]; }
    cs.cum[2] = cum;
    k_cvt_all<<<(int)((cum / 8 + 255) / 256), 256, 0, stream>>>(cs);

    // fragment-packed weights
    k_packB<0><<<32, 256, 0, stream>>>(W_enc_att, nullptr, Wenc_pk, 2048, 0, 0);
    k_packB<1><<<160, 256, 0, stream>>>(W_dec_att, W_beta, Wab_pk, 512, 512, 0);
    k_packB<2><<<128, 256, 0, stream>>>(W_ih, W_hh, Wg_pk, 3072, 0, 2560);
    k_packB<0><<<2000, 256, 0, stream>>>(W_fc, nullptr, Wfc_pk, 512, 0, 0);

    // init: [h|c] = mean_b @ [W_init_h|W_init_c]^T (N-split), then LN
    k_mgemm<4, 1, 0, 0, 0, 0><<<dim3(1, 8, 1), 256, 0, stream>>>(mean_b, 2048, W_inh_b, W_inc_b,
        nullptr, pi, nullptr, 1024, 2048, 1, 512, 64);
    k_initln<<<B_, 512, 0, stream>>>(pi, b_init_h, b_init_c, g_h, be_h, g_c, be_c, xh, cbuf);

    // att1 = enc_pk @ Wenc_pk^T + b -> bf16 [12544][512]; MI=4, 784 blocks XCD-chunked
    k_mgemm<4, 0, 1, 1, 1, 1><<<784, 256, 0, stream>>>(enc_pk, 0, Wenc_pk, nullptr,
        b_enc_att, nullptr, att1_b, 512, 2048, 1, 0, 12544);

    for (int t = 0; t < T_; ++t) {
        // [att2|gate_pre] = h @ packed[W_dec|W_beta]^T (split-K S=4 raw slots)
        k_mgemm<4, 0, 0, 0, 1, 0><<<dim3(1, 20, 4), 256, 0, stream>>>(xh + 2560, 3072, Wab_pk, nullptr,
            nullptr, att2gate, nullptr, 2560, 512, 4, 0, 64);
        k_attn<<<128, 512, 0, stream>>>(att2gate, b_dec_att, b_beta, W_full, att1_b, enc_s,
            caps_i, declen_i, emb, xh, out, t);
        // gates = xh @ packed[W_ih;W_hh]^T (split-K S=8)
        k_mgemm<4, 0, 0, 0, 1, 0><<<dim3(1, 16, 8), 256, 0, stream>>>(xh, 3072, Wg_pk, nullptr,
            nullptr, gp, nullptr, 2048, 3072, 8, 0, 64);
        k_lstm<<<B_, 512, 0, stream>>>(gp, b_ih, b_hh, g_h, be_h, g_c, be_c,
            xh, cbuf, hseq, declen_i, t);
    }

    // pack hseq (rmap gather) then preds with zero-fill merged
    k_packA<<<31, 256, 0, stream>>>(hseq, rmap, Apk);
    k_preds<<<7750, 256, 0, stream>>>(Apk, Wfc_pk, b_fc, orow, mact, out);
}